// Round 10
// baseline (703.149 us; speedup 1.0000x reference)
//
#include <hip/hip_runtime.h>

#define NN 100000
#define FIN 256
#define HD 128
#define CD 64
#define RG 8      // node ranges (12500 nodes -> 50KB LDS bins)
#define RSZ 12500 // NN / RG
#define CH 32     // edge chunks; grid = RG*CH = 256 blocks

typedef __attribute__((ext_vector_type(8))) short bf16x8;
typedef __attribute__((ext_vector_type(4))) float f32x4;
typedef __attribute__((ext_vector_type(2))) float f32x2;
typedef __attribute__((ext_vector_type(4))) unsigned int u32x4;

// ---------- bf16 helpers ----------
__device__ __forceinline__ float bf2f(unsigned int u16) {
    union { unsigned int u; float f; } v;
    v.u = (u16 & 0xffffu) << 16;
    return v.f;
}
__device__ __forceinline__ unsigned short f2bf(float f) {
    union { float f; unsigned int u; } v;
    v.f = f;
    unsigned int u = v.u + 0x7fffu + ((v.u >> 16) & 1u);  // RNE
    return (unsigned short)(u >> 16);
}

// ---------- dtype detection (inputs bf16 vs fp32; measured R3: fp32) ----------
__global__ void k_detect(const unsigned short* __restrict__ x, int* __restrict__ flag) {
    __shared__ int s[256];
    int t = threadIdx.x;
    int c = 0;
    for (int i = t; i < 16384; i += 256) {
        unsigned int e = (x[2 * i] >> 7) & 0xFF;
        c += (e >= 112 && e <= 134) ? 1 : 0;
    }
    s[t] = c;
    __syncthreads();
    for (int off = 128; off > 0; off >>= 1) {
        if (t < off) s[t] += s[t + off];
        __syncthreads();
    }
    if (t == 0) *flag = (s[0] > 8192) ? 1 : 0;  // 1 = inputs are bf16
}

// ---------- pack weight K x COLS into MFMA B-operand order ----------
template <int K, int COLS>
__global__ void k_packW(const void* __restrict__ src, unsigned short* __restrict__ dst,
                        const int* __restrict__ dflag) {
    constexpr int CT = COLS / 16;
    int i = blockIdx.x * 256 + threadIdx.x;
    if (i >= K * COLS) return;
    int j = i & 7;
    int lane = (i >> 3) & 63;
    int rest = i >> 9;
    int ct = rest % CT;
    int kt = rest / CT;
    int k = kt * 32 + (lane >> 4) * 8 + j;
    int c = ct * 16 + (lane & 15);
    int si = k * COLS + c;
    dst[i] = (*dflag) ? ((const unsigned short*)src)[si] : f2bf(((const float*)src)[si]);
}

// ---------- preprocessing: two-level counting sort, ZERO global atomics ----------
// R9: device atomics are memory-side on gfx950 -> zero global atomics.
// R10: XCD-aligned decode r=bid&7 -> WRITE_SIZE 59.7->13.2MB.
// R11: 1024 threads/block -> 4x TLP, latency hidden.
__global__ __launch_bounds__(1024) void k_histL(const int* __restrict__ row,
                                                int* __restrict__ partial, int E) {
    __shared__ int lbin[RSZ];
    int r = blockIdx.x & (RG - 1);   // XCD-aligned: range r -> XCD r
    int c = blockIdx.x >> 3;
    int lo = r * RSZ;
    for (int i = threadIdx.x; i < RSZ; i += 1024) lbin[i] = 0;
    __syncthreads();
    int cs = (E + CH - 1) / CH;
    int e0 = c * cs;
    int e1 = e0 + cs;
    if (e1 > E) e1 = E;
    for (int e = e0 + threadIdx.x; e < e1; e += 1024) {
        unsigned int rr = (unsigned int)row[e];
        if (rr >= NN) rr = 0;
        unsigned int d = rr - (unsigned int)lo;
        if (d < RSZ) atomicAdd(&lbin[d], 1);
    }
    __syncthreads();
    int* pc = partial + (size_t)c * NN + lo;
    for (int i = threadIdx.x; i < RSZ; i += 1024) pc[i] = lbin[i];
}

// partial[c][i] -> exclusive prefix over c (in place); cnt[i] = total
__global__ __launch_bounds__(256) void k_histpre(int* __restrict__ partial,
                                                 int* __restrict__ cnt, int n) {
    int i = blockIdx.x * 256 + threadIdx.x;
    if (i >= n) return;
    int run = 0;
#pragma unroll
    for (int c = 0; c < CH; c++) {
        int t = partial[(size_t)c * NN + i];
        partial[(size_t)c * NN + i] = run;
        run += t;
    }
    cnt[i] = run;
}

__global__ void k_scan_a(const int* __restrict__ cnt, int* __restrict__ bsum, int n) {
    __shared__ int s[256];
    int i = blockIdx.x * 256 + threadIdx.x;
    s[threadIdx.x] = (i < n) ? cnt[i] : 0;
    __syncthreads();
    for (int off = 128; off > 0; off >>= 1) {
        if (threadIdx.x < off) s[threadIdx.x] += s[threadIdx.x + off];
        __syncthreads();
    }
    if (threadIdx.x == 0) bsum[blockIdx.x] = s[0];
}

__global__ void k_scan_b(int* bsum, int nchunks) {
    __shared__ int s[512];
    int t = threadIdx.x;
    int v = (t < nchunks) ? bsum[t] : 0;
    s[t] = v;
    __syncthreads();
    for (int off = 1; off < 512; off <<= 1) {
        int x = (t >= off) ? s[t - off] : 0;
        __syncthreads();
        s[t] += x;
        __syncthreads();
    }
    if (t < nchunks) bsum[t] = s[t] - v;  // exclusive
}

__global__ void k_scan_c(const int* __restrict__ cnt, const int* __restrict__ bsum,
                         int* __restrict__ offs, int n) {
    __shared__ int s[256];
    int t = threadIdx.x;
    int i = blockIdx.x * 256 + t;
    int v = (i < n) ? cnt[i] : 0;
    s[t] = v;
    __syncthreads();
    for (int off = 1; off < 256; off <<= 1) {
        int x = (t >= off) ? s[t - off] : 0;
        __syncthreads();
        s[t] += x;
        __syncthreads();
    }
    if (i < n) offs[i] = bsum[blockIdx.x] + s[t] - v;
}

// atomic-free scatter: LDS cursor seeded with global base + chunk prefix
__global__ __launch_bounds__(1024) void k_scatL(const int* __restrict__ row,
                                                const int* __restrict__ col,
                                                const int* __restrict__ offs,
                                                const int* __restrict__ partial,
                                                int* __restrict__ colS, int E) {
    __shared__ int lcur[RSZ];
    int r = blockIdx.x & (RG - 1);   // XCD-aligned: range r -> XCD r (R10)
    int c = blockIdx.x >> 3;
    int lo = r * RSZ;
    const int* pc = partial + (size_t)c * NN + lo;
    const int* po = offs + lo;
    for (int i = threadIdx.x; i < RSZ; i += 1024) lcur[i] = po[i] + pc[i];
    __syncthreads();
    int cs = (E + CH - 1) / CH;
    int e0 = c * cs;
    int e1 = e0 + cs;
    if (e1 > E) e1 = E;
    for (int e = e0 + threadIdx.x; e < e1; e += 1024) {
        unsigned int rr = (unsigned int)row[e];
        if (rr >= NN) rr = 0;
        unsigned int d = rr - (unsigned int)lo;
        if (d < RSZ) {
            unsigned int cc = (unsigned int)col[e];
            if (cc >= NN) cc = 0;
            int p = atomicAdd(&lcur[d], 1);
            colS[p] = (int)cc;
        }
    }
}

__global__ void k_dinv(const int* __restrict__ cnt, float* __restrict__ dinv, int n) {
    int i = blockIdx.x * 256 + threadIdx.x;
    if (i < n) dinv[i] = rsqrtf((float)(cnt[i] + 1));  // +1 self loop
}

// ---------- MFMA GEMM: G[r][c] = dinv[r] * sum_k relu?(A[r][k]) * W[k][c]; G bf16 ----------
// R12: LDS W-staging for K*COLS*2 <= 32KB (layers 1-3).
// R13: nontemporal stores reverted.
// R14: A-fragments staged into afr[KT] (deep MLP) — gemm left the top-5.
template <int K, int COLS, bool RELU, int AMODE>
__global__ __launch_bounds__(256) void k_gemm(const void* __restrict__ Av,
                                              const unsigned short* __restrict__ Wp,
                                              const float* __restrict__ dinv,
                                              unsigned short* __restrict__ G, int nrows,
                                              const int* __restrict__ dflag) {
    constexpr int CT = COLS / 16;
    constexpr int KT = K / 32;
    constexpr bool SW = (K * COLS * 2) <= 32768;  // stage W in LDS?
    __shared__ unsigned short tile[4][16][136];
    __shared__ unsigned short ldsW[SW ? (K * COLS) : 8];

    int t = threadIdx.x;
    int wave = t >> 6, lane = t & 63;
    int quad = lane >> 4, m = lane & 15;
    int r0 = blockIdx.x * 64 + wave * 16;
    int arow = r0 + m;
    bool rowok = arow < nrows;
    bool abf = (AMODE == 0) || (*dflag != 0);

    const unsigned short* Ab = (const unsigned short*)Av;
    const float* Af = (const float*)Av;

    if constexpr (SW) {
        const u32x4* src = (const u32x4*)Wp;
        u32x4* dst = (u32x4*)ldsW;
        for (int i = t; i < K * COLS / 8; i += 256) dst[i] = src[i];
        __syncthreads();
    }

    // ---- R14: stage all A-fragments (deep MLP) ----
    bf16x8 afr[KT];
#pragma unroll
    for (int kt = 0; kt < KT; kt++) afr[kt] = (bf16x8)0;
    if (rowok) {
        if (abf) {
#pragma unroll
            for (int kt = 0; kt < KT; kt++)
                afr[kt] = *(const bf16x8*)(Ab + (size_t)arow * K + kt * 32 + quad * 8);
            if constexpr (RELU) {
#pragma unroll
                for (int kt = 0; kt < KT; kt++) {
#pragma unroll
                    for (int j = 0; j < 8; j++) {
                        unsigned short u = (unsigned short)afr[kt][j];
                        afr[kt][j] = (u & 0x8000u) ? (short)0 : (short)u;
                    }
                }
            }
        } else {
#pragma unroll
            for (int kt = 0; kt < KT; kt++) {
                float4 f0 = *(const float4*)(Af + (size_t)arow * K + kt * 32 + quad * 8);
                float4 f1 = *(const float4*)(Af + (size_t)arow * K + kt * 32 + quad * 8 + 4);
                afr[kt][0] = (short)f2bf(f0.x); afr[kt][1] = (short)f2bf(f0.y);
                afr[kt][2] = (short)f2bf(f0.z); afr[kt][3] = (short)f2bf(f0.w);
                afr[kt][4] = (short)f2bf(f1.x); afr[kt][5] = (short)f2bf(f1.y);
                afr[kt][6] = (short)f2bf(f1.z); afr[kt][7] = (short)f2bf(f1.w);
            }
        }
    }

    f32x4 acc[CT];
#pragma unroll
    for (int ct = 0; ct < CT; ct++) acc[ct] = (f32x4){0.f, 0.f, 0.f, 0.f};

#pragma unroll
    for (int kt = 0; kt < KT; kt++) {
#pragma unroll
        for (int ct = 0; ct < CT; ct++) {
            bf16x8 bfrag;
            if constexpr (SW)
                bfrag = *(const bf16x8*)&ldsW[(((size_t)kt * CT + ct) * 64 + lane) * 8];
            else
                bfrag = *(const bf16x8*)(Wp + (((size_t)kt * CT + ct) * 64 + lane) * 8);
            acc[ct] = __builtin_amdgcn_mfma_f32_16x16x32_bf16(afr[kt], bfrag, acc[ct], 0, 0, 0);
        }
    }

    float dv[4];
#pragma unroll
    for (int rg = 0; rg < 4; rg++) {
        int gr = r0 + quad * 4 + rg;
        dv[rg] = dinv[gr < nrows ? gr : 0];
    }
#pragma unroll
    for (int ct = 0; ct < CT; ct++) {
#pragma unroll
        for (int rg = 0; rg < 4; rg++)
            tile[wave][quad * 4 + rg][ct * 16 + m] = f2bf(acc[ct][rg] * dv[rg]);
    }
    int srow = lane >> 2;
    int grow = r0 + srow;
    if (grow < nrows) {
        constexpr int CH2 = COLS / 32;
#pragma unroll
        for (int j8 = 0; j8 < CH2; j8++) {
            int c = (lane & 3) * 8 + j8 * 32;
            uint4 v = *(const uint4*)&tile[wave][srow][c];
            *(uint4*)(G + (size_t)grow * COLS + c) = v;
        }
    }
}

// ---------- aggregate: out[r] = relu?(dinv[r]*(g[r] + sum_{c in adj(r)} g[c])) ----------
// R8: wide dwordx4 loads — one load fetches 4 (D=128) / 8 (D=64) neighbor rows.
// R15: packed f32x2 accumulators. Per u32 (2 bf16): {u<<16, u&0xffff0000} + one
// v_pk_add_f32 = 3 VALU vs old 4 (2 cvt + 2 scalar add); scale/relu also packed.
// agg is mixed ~50% VALU / ~45% mem with FETCH already at the cache-topology
// floor (191.8MB vs ~205MB compulsory), so VALU is the remaining lever.
__device__ __forceinline__ f32x2 bfpair(unsigned int u) {
    union { unsigned int u; float f; } lo, hi;
    lo.u = u << 16;
    hi.u = u & 0xffff0000u;
    return (f32x2){lo.f, hi.f};
}
__device__ __forceinline__ void acc8p(f32x2* a, uint4 u) {
    a[0] += bfpair(u.x);
    a[1] += bfpair(u.y);
    a[2] += bfpair(u.z);
    a[3] += bfpair(u.w);
}

template <int D, bool RELU, bool FINAL>
__global__ __launch_bounds__(256) void k_agg(const unsigned short* __restrict__ g,
                                             const int* __restrict__ colS,
                                             const int* __restrict__ offs,
                                             const int* __restrict__ cnt,
                                             const float* __restrict__ dinv,
                                             unsigned short* __restrict__ obf,
                                             void* __restrict__ oraw,
                                             const int* __restrict__ dflag, int n) {
    constexpr int GRP = (D == 128) ? 4 : 8;   // neighbor rows per load instruction
    constexpr int LPR = 64 / GRP;             // lanes per row (16 or 8)
    int lane = threadIdx.x & 63;
    int node = blockIdx.x * 4 + (threadIdx.x >> 6);
    if (node >= n) return;
    int gq = lane / LPR;      // neighbor slot within a GRP-group
    int li = lane % LPR;      // 16B chunk within the row (covers cols li*8..li*8+7)
    int start = offs[node];
    int deg = cnt[node];

    f32x2 a[4];               // a[i] = cols (li*8+2i, li*8+2i+1)
#pragma unroll
    for (int i = 0; i < 4; i++) a[i] = (f32x2){0.f, 0.f};

    // self row (group 0 only)
    if (gq == 0) {
        uint4 u = *(const uint4*)(g + (size_t)node * D + li * 8);
        acc8p(a, u);
    }

    for (int base = 0; base < deg; base += 64) {
        int rem = deg - base;
        int nb = rem < 64 ? rem : 64;
        int cidx = 0;
        if (lane < nb) cidx = colS[start + base + lane];
        int j = 0;
        if constexpr (D == 128) {
            for (; j + 8 <= nb; j += 8) {
                int ca = __shfl(cidx, j + gq);
                int cb = __shfl(cidx, j + 4 + gq);
                uint4 ua = *(const uint4*)(g + (size_t)ca * D + li * 8);
                uint4 ub = *(const uint4*)(g + (size_t)cb * D + li * 8);
                acc8p(a, ua);
                acc8p(a, ub);
            }
            for (; j < nb; j += 4) {
                int jj = j + gq;
                int cc = __shfl(cidx, jj < nb ? jj : (nb - 1));
                if (jj < nb) {
                    uint4 u = *(const uint4*)(g + (size_t)cc * D + li * 8);
                    acc8p(a, u);
                }
            }
        } else {
            for (; j + 8 <= nb; j += 8) {
                int cc = __shfl(cidx, j + gq);
                uint4 u = *(const uint4*)(g + (size_t)cc * D + li * 8);
                acc8p(a, u);
            }
            for (; j < nb; j += 8) {
                int jj = j + gq;
                int cc = __shfl(cidx, jj < nb ? jj : (nb - 1));
                if (jj < nb) {
                    uint4 u = *(const uint4*)(g + (size_t)cc * D + li * 8);
                    acc8p(a, u);
                }
            }
        }
    }

    // cross-group reduce: lanes sharing li sum over the GRP neighbor slots
#pragma unroll
    for (int i = 0; i < 4; i++) {
        if constexpr (D == 64) {
            a[i].x += __shfl_xor(a[i].x, 8);
            a[i].y += __shfl_xor(a[i].y, 8);
        }
        a[i].x += __shfl_xor(a[i].x, 16);
        a[i].y += __shfl_xor(a[i].y, 16);
        a[i].x += __shfl_xor(a[i].x, 32);
        a[i].y += __shfl_xor(a[i].y, 32);
    }

    float s = dinv[node];
    f32x2 sv = {s, s};
#pragma unroll
    for (int i = 0; i < 4; i++) {
        a[i] *= sv;
        if constexpr (RELU)
            a[i] = (f32x2){fmaxf(a[i].x, 0.f), fmaxf(a[i].y, 0.f)};
    }

    if (gq == 0) {
        uint4 o;
        o.x = (unsigned int)f2bf(a[0].x) | ((unsigned int)f2bf(a[0].y) << 16);
        o.y = (unsigned int)f2bf(a[1].x) | ((unsigned int)f2bf(a[1].y) << 16);
        o.z = (unsigned int)f2bf(a[2].x) | ((unsigned int)f2bf(a[2].y) << 16);
        o.w = (unsigned int)f2bf(a[3].x) | ((unsigned int)f2bf(a[3].y) << 16);
        *(uint4*)(obf + (size_t)node * D + li * 8) = o;
        if constexpr (FINAL) {
            if (*dflag) {
                *(uint4*)((unsigned short*)oraw + (size_t)node * D + li * 8) = o;
            } else {
                float* op = (float*)oraw + (size_t)node * D + li * 8;
                *(float4*)op = (float4){a[0].x, a[0].y, a[1].x, a[1].y};
                *(float4*)(op + 4) = (float4){a[2].x, a[2].y, a[3].x, a[3].y};
            }
        }
    }
}

// ---------- column sums (vectorized bf16x8 loads + LDS reduce) ----------
template <int D>
__global__ __launch_bounds__(256) void k_colsum(const unsigned short* __restrict__ in,
                                                float* __restrict__ colsum, int n) {
    constexpr int CG = D / 8;
    constexpr int RPB = 256 / CG;
    __shared__ float red[RPB][D];
    int t = threadIdx.x;
    int cg = t % CG, r0 = t / CG;
    int c0 = cg * 8;
    float a[8];
#pragma unroll
    for (int i = 0; i < 8; i++) a[i] = 0.f;
    for (int r = blockIdx.x * RPB + r0; r < n; r += gridDim.x * RPB) {
        bf16x8 u = *(const bf16x8*)(in + (size_t)r * D + c0);
#pragma unroll
        for (int i = 0; i < 8; i++) a[i] += bf2f((unsigned short)u[i]);
    }
#pragma unroll
    for (int i = 0; i < 8; i++) red[r0][c0 + i] = a[i];
    __syncthreads();
    if (t < D) {
        float s = 0.f;
#pragma unroll
        for (int r = 0; r < RPB; r++) s += red[r][t];
        atomicAdd(&colsum[t], s);
    }
}

// ---------- MFMA covariance (see R6 notes: no dynamic register indexing) ----------
template <int D>
__global__ __launch_bounds__(256) void k_cov2(const unsigned short* __restrict__ in,
                                              const float* __restrict__ colsum,
                                              float* __restrict__ part, int n, int nblocks) {
    constexpr int CT = D / 16;
    constexpr int TPW = (D == 128) ? 2 : 1;
    constexpr int CG = D / 8;
    __shared__ unsigned int lds32[D * 16];
    __shared__ float smean[D];

    int t = threadIdx.x;
    int wave = t >> 6, lane = t & 63;
    int quad = lane >> 4, m = lane & 15;

    if (t < D) smean[t] = colsum[t] * (1.0f / (float)NN);
    __syncthreads();

    f32x4 accA[CT], accB[CT];
#pragma unroll
    for (int tc = 0; tc < CT; tc++) {
        accA[tc] = (f32x4){0.f, 0.f, 0.f, 0.f};
        accB[tc] = (f32x4){0.f, 0.f, 0.f, 0.f};
    }

    bool stager = (t < 16 * CG);
    int kp = stager ? (t / CG) : 0;
    int c0 = stager ? ((t % CG) * 8) : 0;
    int slot = (((kp >> 2) + (c0 >> 3)) & 3) * 4 + (kp & 3);
    float sm[8];
#pragma unroll
    for (int i = 0; i < 8; i++) sm[i] = smean[c0 + i];

    int ca0 = (wave * TPW) * 16 + m;
    int ga0 = (quad + (ca0 >> 3)) & 3;
    int ca1 = ca0 + 16;
    int ga1 = (quad + (ca1 >> 3)) & 3;

    int nchunks = (n + 31) / 32;
    for (int ch = blockIdx.x; ch < nchunks; ch += nblocks) {
        int k0 = ch * 32;
        if (stager) {
            int k = k0 + 2 * kp;
            bf16x8 u0 = (bf16x8)0, u1 = (bf16x8)0;
            bool ok0 = (k < n), ok1 = (k + 1 < n);
            if (ok0) u0 = *(const bf16x8*)(in + (size_t)k * D + c0);
            if (ok1) u1 = *(const bf16x8*)(in + (size_t)(k + 1) * D + c0);
#pragma unroll
            for (int i = 0; i < 8; i++) {
                float a = ok0 ? (bf2f((unsigned short)u0[i]) - sm[i]) : 0.f;
                float b = ok1 ? (bf2f((unsigned short)u1[i]) - sm[i]) : 0.f;
                lds32[(c0 + i) * 16 + slot] = (unsigned int)f2bf(a) | ((unsigned int)f2bf(b) << 16);
            }
        }
        __syncthreads();

        bf16x8 bfr[CT];
#pragma unroll
        for (int tc = 0; tc < CT; tc++) {
            int c = tc * 16 + m;
            int grp = (quad + (c >> 3)) & 3;
            bfr[tc] = *(const bf16x8*)&lds32[c * 16 + grp * 4];
        }
        bf16x8 afr0 = *(const bf16x8*)&lds32[ca0 * 16 + ga0 * 4];
#pragma unroll
        for (int tc = 0; tc < CT; tc++)
            accA[tc] = __builtin_amdgcn_mfma_f32_16x16x32_bf16(afr0, bfr[tc], accA[tc], 0, 0, 0);
        if constexpr (TPW == 2) {
            bf16x8 afr1 = *(const bf16x8*)&lds32[ca1 * 16 + ga1 * 4];
#pragma unroll
            for (int tc = 0; tc < CT; tc++)
                accB[tc] = __builtin_amdgcn_mfma_f32_16x16x32_bf16(afr1, bfr[tc], accB[tc], 0, 0, 0);
        }
        __syncthreads();
    }

    float* p = part + (size_t)blockIdx.x * D * D;
    int tr0 = wave * TPW;
#pragma unroll
    for (int tc = 0; tc < CT; tc++) {
#pragma unroll
        for (int rg = 0; rg < 4; rg++) {
            int cj = tc * 16 + m;
            p[(tr0 * 16 + quad * 4 + rg) * D + cj] = accA[tc][rg];
            if constexpr (TPW == 2)
                p[((tr0 + 1) * 16 + quad * 4 + rg) * D + cj] = accB[tc][rg];
        }
    }
}

// ---------- partial-covariance reduction (R7: 2-D decomposition) ----------
template <int D>
__global__ __launch_bounds__(256) void k_covred(const float* __restrict__ part,
                                                float* __restrict__ cov, int nblocks) {
    __shared__ float red[256];
    int t = threadIdx.x;
    int il = t & 63;          // output index within block's chunk
    int bs = t >> 6;          // b-slice 0..3 (one per wave)
    int idx = blockIdx.x * 64 + il;
    float s = 0.f;
    for (int b = bs; b < nblocks; b += 4)
        s += part[(size_t)b * D * D + idx];
    red[t] = s;
    __syncthreads();
    if (t < 64)
        cov[idx] = red[t] + red[t + 64] + red[t + 128] + red[t + 192];
}

template <int D>
__global__ __launch_bounds__(256) void k_fin(const float* __restrict__ cov,
                                             void* __restrict__ out, long long idx,
                                             const int* __restrict__ dflag) {
    __shared__ float sd[D];
    __shared__ float red[256];
    int t = threadIdx.x;
    if (t < D) sd[t] = sqrtf(fmaxf(cov[t * D + t], 1e-12f));
    __syncthreads();
    float s = 0.f;
    for (int i2 = t; i2 < D * D; i2 += 256) {
        int i = i2 / D, j = i2 % D;
        if (j > i) s += fabsf(cov[i2] / (sd[i] * sd[j]));
    }
    red[t] = s;
    __syncthreads();
    for (int off = 128; off > 0; off >>= 1) {
        if (t < off) red[t] += red[t + off];
        __syncthreads();
    }
    if (t == 0) {
        float v = red[0] / (float)(D * (D - 1) / 2);
        if (*dflag) ((unsigned short*)out)[idx] = f2bf(v);
        else        ((float*)out)[idx] = v;
    }
}

// ---------- launch ----------
extern "C" void kernel_launch(void* const* d_in, const int* in_sizes, int n_in,
                              void* d_out, int out_size, void* d_ws, size_t ws_size,
                              hipStream_t stream) {
    const void* x = d_in[0];
    const int* ei = (const int*)d_in[1];

    int E = in_sizes[1] / 2;
    const int* row = ei;
    const int* col = ei + E;

    char* w = (char*)d_ws;
    auto carve = [&](size_t bytes) {
        void* p = (void*)w;
        w += (bytes + 255) & ~(size_t)255;
        return p;
    };
    int* cnt = (int*)carve((size_t)NN * 4);
    int* offs = (int*)carve((size_t)NN * 4);
    int* bsum = (int*)carve(512 * 4);
    int* colS = (int*)carve((size_t)E * 4);
    float* dinv = (float*)carve((size_t)NN * 4);
    float* colsum = (float*)carve(HD * 4);
    float* covs = (float*)carve(HD * HD * 4);
    int* dflag = (int*)carve(256);
    unsigned short* wc = (unsigned short*)carve((size_t)(FIN * HD + HD * HD * 2 + HD * CD) * 2);
    unsigned short* bufA = (unsigned short*)carve((size_t)NN * HD * 2);
    unsigned short* bufB = (unsigned short*)carve((size_t)NN * HD * 2);

    unsigned short* wc0 = wc;              // 256x128 packed
    unsigned short* wc1 = wc + FIN * HD;   // 128x128 packed
    unsigned short* wc2 = wc1 + HD * HD;   // 128x128 packed
    unsigned short* wc3 = wc2 + HD * HD;   // 128x64 packed

    float* part = (float*)bufB;   // cov partials alias bufB (dead during corr)
    int* chp = (int*)bufB;        // chunk-prefix partials alias bufB (dead in preprocessing; 12.8MB <= 25.6MB)
    const int NBC = 250;

    int nchunks = (NN + 255) / 256;
    int GB = (NN + 63) / 64;

    // dtype detection + weight packing
    k_detect<<<1, 256, 0, stream>>>((const unsigned short*)x, dflag);
    k_packW<256, 128><<<(FIN * HD) / 256, 256, 0, stream>>>(d_in[2], wc0, dflag);
    k_packW<128, 128><<<(HD * HD) / 256, 256, 0, stream>>>(d_in[3], wc1, dflag);
    k_packW<128, 128><<<(HD * HD) / 256, 256, 0, stream>>>(d_in[4], wc2, dflag);
    k_packW<128, 64><<<(HD * CD) / 256, 256, 0, stream>>>(d_in[5], wc3, dflag);

    // preprocessing (CSR by destination) — zero global atomics (R9), XCD-aligned (R10),
    // 1024-thread latency hiding (R11)
    k_histL<<<RG * CH, 1024, 0, stream>>>(row, chp, E);
    k_histpre<<<nchunks, 256, 0, stream>>>(chp, cnt, NN);
    k_scan_a<<<nchunks, 256, 0, stream>>>(cnt, bsum, NN);
    k_scan_b<<<1, 512, 0, stream>>>(bsum, nchunks);
    k_scan_c<<<nchunks, 256, 0, stream>>>(cnt, bsum, offs, NN);
    k_scatL<<<RG * CH, 1024, 0, stream>>>(row, col, offs, chp, colS, E);
    k_dinv<<<nchunks, 256, 0, stream>>>(cnt, dinv, NN);

    // layer 0
    k_gemm<256, 128, false, 2><<<GB, 256, 0, stream>>>(x, wc0, dinv, bufB, NN, dflag);
    k_agg<128, true, false><<<NN / 4, 256, 0, stream>>>(bufB, colS, offs, cnt, dinv, bufA, nullptr, dflag, NN);
    // layer 1
    k_gemm<128, 128, false, 0><<<GB, 256, 0, stream>>>(bufA, wc1, dinv, bufB, NN, dflag);
    k_agg<128, true, false><<<NN / 4, 256, 0, stream>>>(bufB, colS, offs, cnt, dinv, bufA, nullptr, dflag, NN);
    // layer 2 (pre-ReLU kept in bufA for corr_2)
    k_gemm<128, 128, false, 0><<<GB, 256, 0, stream>>>(bufA, wc2, dinv, bufB, NN, dflag);
    k_agg<128, false, false><<<NN / 4, 256, 0, stream>>>(bufB, colS, offs, cnt, dinv, bufA, nullptr, dflag, NN);

    // corr_2 on bufA (bf16, D=128)
    hipMemsetAsync(colsum, 0, HD * 4, stream);
    k_colsum<128><<<64, 256, 0, stream>>>(bufA, colsum, NN);
    k_cov2<128><<<NBC, 256, 0, stream>>>(bufA, colsum, part, NN, NBC);
    k_covred<128><<<(HD * HD) / 64, 256, 0, stream>>>(part, covs, NBC);
    k_fin<128><<<1, 256, 0, stream>>>(covs, d_out, (long long)NN * CD, dflag);

    // layer 3: relu(bufA) @ W3 -> bufB ; aggregate -> d_out (+ bf16 mirror in bufA)
    k_gemm<128, 64, true, 0><<<GB, 256, 0, stream>>>(bufA, wc3, dinv, bufB, NN, dflag);
    k_agg<64, false, true><<<NN / 4, 256, 0, stream>>>(bufB, colS, offs, cnt, dinv, bufA, d_out, dflag, NN);

    // corr on final output (bf16 mirror in bufA, D=64)
    hipMemsetAsync(colsum, 0, HD * 4, stream);
    k_colsum<64><<<64, 256, 0, stream>>>(bufA, colsum, NN);
    k_cov2<64><<<NBC, 256, 0, stream>>>(bufA, colsum, part, NN, NBC);
    k_covred<64><<<(CD * CD) / 64, 256, 0, stream>>>(part, covs, NBC);
    k_fin<64><<<1, 256, 0, stream>>>(covs, d_out, (long long)NN * CD + 1, dflag);
}

// Round 11
// 683.303 us; speedup vs baseline: 1.0290x; 1.0290x over previous
//
#include <hip/hip_runtime.h>

#define NN 100000
#define FIN 256
#define HD 128
#define CD 64
#define RG 8      // node ranges (12500 nodes -> 50KB LDS bins)
#define RSZ 12500 // NN / RG
#define CH 32     // edge chunks; grid = RG*CH = 256 blocks

typedef __attribute__((ext_vector_type(8))) short bf16x8;
typedef __attribute__((ext_vector_type(4))) float f32x4;
typedef __attribute__((ext_vector_type(2))) float f32x2;
typedef __attribute__((ext_vector_type(4))) unsigned int u32x4;

// ---------- bf16 helpers ----------
__device__ __forceinline__ float bf2f(unsigned int u16) {
    union { unsigned int u; float f; } v;
    v.u = (u16 & 0xffffu) << 16;
    return v.f;
}
__device__ __forceinline__ unsigned short f2bf(float f) {
    union { float f; unsigned int u; } v;
    v.f = f;
    unsigned int u = v.u + 0x7fffu + ((v.u >> 16) & 1u);  // RNE
    return (unsigned short)(u >> 16);
}

// ---------- dtype detection (inputs bf16 vs fp32; measured R3: fp32) ----------
__global__ void k_detect(const unsigned short* __restrict__ x, int* __restrict__ flag) {
    __shared__ int s[256];
    int t = threadIdx.x;
    int c = 0;
    for (int i = t; i < 16384; i += 256) {
        unsigned int e = (x[2 * i] >> 7) & 0xFF;
        c += (e >= 112 && e <= 134) ? 1 : 0;
    }
    s[t] = c;
    __syncthreads();
    for (int off = 128; off > 0; off >>= 1) {
        if (t < off) s[t] += s[t + off];
        __syncthreads();
    }
    if (t == 0) *flag = (s[0] > 8192) ? 1 : 0;  // 1 = inputs are bf16
}

// ---------- pack weight K x COLS into MFMA B-operand order ----------
template <int K, int COLS>
__global__ void k_packW(const void* __restrict__ src, unsigned short* __restrict__ dst,
                        const int* __restrict__ dflag) {
    constexpr int CT = COLS / 16;
    int i = blockIdx.x * 256 + threadIdx.x;
    if (i >= K * COLS) return;
    int j = i & 7;
    int lane = (i >> 3) & 63;
    int rest = i >> 9;
    int ct = rest % CT;
    int kt = rest / CT;
    int k = kt * 32 + (lane >> 4) * 8 + j;
    int c = ct * 16 + (lane & 15);
    int si = k * COLS + c;
    dst[i] = (*dflag) ? ((const unsigned short*)src)[si] : f2bf(((const float*)src)[si]);
}

// ---------- preprocessing: two-level counting sort, ZERO global atomics ----------
// R9: device atomics are memory-side on gfx950 -> zero global atomics.
// R10: XCD-aligned decode r=bid&7 -> WRITE_SIZE 59.7->13.2MB.
// R11: 1024 threads/block -> 4x TLP, latency hidden.
__global__ __launch_bounds__(1024) void k_histL(const int* __restrict__ row,
                                                int* __restrict__ partial, int E) {
    __shared__ int lbin[RSZ];
    int r = blockIdx.x & (RG - 1);   // XCD-aligned: range r -> XCD r
    int c = blockIdx.x >> 3;
    int lo = r * RSZ;
    for (int i = threadIdx.x; i < RSZ; i += 1024) lbin[i] = 0;
    __syncthreads();
    int cs = (E + CH - 1) / CH;
    int e0 = c * cs;
    int e1 = e0 + cs;
    if (e1 > E) e1 = E;
    for (int e = e0 + threadIdx.x; e < e1; e += 1024) {
        unsigned int rr = (unsigned int)row[e];
        if (rr >= NN) rr = 0;
        unsigned int d = rr - (unsigned int)lo;
        if (d < RSZ) atomicAdd(&lbin[d], 1);
    }
    __syncthreads();
    int* pc = partial + (size_t)c * NN + lo;
    for (int i = threadIdx.x; i < RSZ; i += 1024) pc[i] = lbin[i];
}

// partial[c][i] -> exclusive prefix over c (in place); cnt[i] = total
__global__ __launch_bounds__(256) void k_histpre(int* __restrict__ partial,
                                                 int* __restrict__ cnt, int n) {
    int i = blockIdx.x * 256 + threadIdx.x;
    if (i >= n) return;
    int run = 0;
#pragma unroll
    for (int c = 0; c < CH; c++) {
        int t = partial[(size_t)c * NN + i];
        partial[(size_t)c * NN + i] = run;
        run += t;
    }
    cnt[i] = run;
}

__global__ void k_scan_a(const int* __restrict__ cnt, int* __restrict__ bsum, int n) {
    __shared__ int s[256];
    int i = blockIdx.x * 256 + threadIdx.x;
    s[threadIdx.x] = (i < n) ? cnt[i] : 0;
    __syncthreads();
    for (int off = 128; off > 0; off >>= 1) {
        if (threadIdx.x < off) s[threadIdx.x] += s[threadIdx.x + off];
        __syncthreads();
    }
    if (threadIdx.x == 0) bsum[blockIdx.x] = s[0];
}

__global__ void k_scan_b(int* bsum, int nchunks) {
    __shared__ int s[512];
    int t = threadIdx.x;
    int v = (t < nchunks) ? bsum[t] : 0;
    s[t] = v;
    __syncthreads();
    for (int off = 1; off < 512; off <<= 1) {
        int x = (t >= off) ? s[t - off] : 0;
        __syncthreads();
        s[t] += x;
        __syncthreads();
    }
    if (t < nchunks) bsum[t] = s[t] - v;  // exclusive
}

__global__ void k_scan_c(const int* __restrict__ cnt, const int* __restrict__ bsum,
                         int* __restrict__ offs, int n) {
    __shared__ int s[256];
    int t = threadIdx.x;
    int i = blockIdx.x * 256 + t;
    int v = (i < n) ? cnt[i] : 0;
    s[t] = v;
    __syncthreads();
    for (int off = 1; off < 256; off <<= 1) {
        int x = (t >= off) ? s[t - off] : 0;
        __syncthreads();
        s[t] += x;
        __syncthreads();
    }
    if (i < n) offs[i] = bsum[blockIdx.x] + s[t] - v;
}

// atomic-free scatter: LDS cursor seeded with global base + chunk prefix
__global__ __launch_bounds__(1024) void k_scatL(const int* __restrict__ row,
                                                const int* __restrict__ col,
                                                const int* __restrict__ offs,
                                                const int* __restrict__ partial,
                                                int* __restrict__ colS, int E) {
    __shared__ int lcur[RSZ];
    int r = blockIdx.x & (RG - 1);   // XCD-aligned: range r -> XCD r (R10)
    int c = blockIdx.x >> 3;
    int lo = r * RSZ;
    const int* pc = partial + (size_t)c * NN + lo;
    const int* po = offs + lo;
    for (int i = threadIdx.x; i < RSZ; i += 1024) lcur[i] = po[i] + pc[i];
    __syncthreads();
    int cs = (E + CH - 1) / CH;
    int e0 = c * cs;
    int e1 = e0 + cs;
    if (e1 > E) e1 = E;
    for (int e = e0 + threadIdx.x; e < e1; e += 1024) {
        unsigned int rr = (unsigned int)row[e];
        if (rr >= NN) rr = 0;
        unsigned int d = rr - (unsigned int)lo;
        if (d < RSZ) {
            unsigned int cc = (unsigned int)col[e];
            if (cc >= NN) cc = 0;
            int p = atomicAdd(&lcur[d], 1);
            colS[p] = (int)cc;
        }
    }
}

__global__ void k_dinv(const int* __restrict__ cnt, float* __restrict__ dinv, int n) {
    int i = blockIdx.x * 256 + threadIdx.x;
    if (i < n) dinv[i] = rsqrtf((float)(cnt[i] + 1));  // +1 self loop
}

// ---------- MFMA GEMM: G[r][c] = dinv[r] * sum_k relu?(A[r][k]) * W[k][c]; G bf16 ----------
// R12: LDS W-staging for K*COLS*2 <= 32KB. R13: NT stores reverted.
// R14: A-fragments staged into afr[KT] (deep MLP).
template <int K, int COLS, bool RELU, int AMODE>
__global__ __launch_bounds__(256) void k_gemm(const void* __restrict__ Av,
                                              const unsigned short* __restrict__ Wp,
                                              const float* __restrict__ dinv,
                                              unsigned short* __restrict__ G, int nrows,
                                              const int* __restrict__ dflag) {
    constexpr int CT = COLS / 16;
    constexpr int KT = K / 32;
    constexpr bool SW = (K * COLS * 2) <= 32768;  // stage W in LDS?
    __shared__ unsigned short tile[4][16][136];
    __shared__ unsigned short ldsW[SW ? (K * COLS) : 8];

    int t = threadIdx.x;
    int wave = t >> 6, lane = t & 63;
    int quad = lane >> 4, m = lane & 15;
    int r0 = blockIdx.x * 64 + wave * 16;
    int arow = r0 + m;
    bool rowok = arow < nrows;
    bool abf = (AMODE == 0) || (*dflag != 0);

    const unsigned short* Ab = (const unsigned short*)Av;
    const float* Af = (const float*)Av;

    if constexpr (SW) {
        const u32x4* src = (const u32x4*)Wp;
        u32x4* dst = (u32x4*)ldsW;
        for (int i = t; i < K * COLS / 8; i += 256) dst[i] = src[i];
        __syncthreads();
    }

    bf16x8 afr[KT];
#pragma unroll
    for (int kt = 0; kt < KT; kt++) afr[kt] = (bf16x8)0;
    if (rowok) {
        if (abf) {
#pragma unroll
            for (int kt = 0; kt < KT; kt++)
                afr[kt] = *(const bf16x8*)(Ab + (size_t)arow * K + kt * 32 + quad * 8);
            if constexpr (RELU) {
#pragma unroll
                for (int kt = 0; kt < KT; kt++) {
#pragma unroll
                    for (int j = 0; j < 8; j++) {
                        unsigned short u = (unsigned short)afr[kt][j];
                        afr[kt][j] = (u & 0x8000u) ? (short)0 : (short)u;
                    }
                }
            }
        } else {
#pragma unroll
            for (int kt = 0; kt < KT; kt++) {
                float4 f0 = *(const float4*)(Af + (size_t)arow * K + kt * 32 + quad * 8);
                float4 f1 = *(const float4*)(Af + (size_t)arow * K + kt * 32 + quad * 8 + 4);
                afr[kt][0] = (short)f2bf(f0.x); afr[kt][1] = (short)f2bf(f0.y);
                afr[kt][2] = (short)f2bf(f0.z); afr[kt][3] = (short)f2bf(f0.w);
                afr[kt][4] = (short)f2bf(f1.x); afr[kt][5] = (short)f2bf(f1.y);
                afr[kt][6] = (short)f2bf(f1.z); afr[kt][7] = (short)f2bf(f1.w);
            }
        }
    }

    f32x4 acc[CT];
#pragma unroll
    for (int ct = 0; ct < CT; ct++) acc[ct] = (f32x4){0.f, 0.f, 0.f, 0.f};

#pragma unroll
    for (int kt = 0; kt < KT; kt++) {
#pragma unroll
        for (int ct = 0; ct < CT; ct++) {
            bf16x8 bfrag;
            if constexpr (SW)
                bfrag = *(const bf16x8*)&ldsW[(((size_t)kt * CT + ct) * 64 + lane) * 8];
            else
                bfrag = *(const bf16x8*)(Wp + (((size_t)kt * CT + ct) * 64 + lane) * 8);
            acc[ct] = __builtin_amdgcn_mfma_f32_16x16x32_bf16(afr[kt], bfrag, acc[ct], 0, 0, 0);
        }
    }

    float dv[4];
#pragma unroll
    for (int rg = 0; rg < 4; rg++) {
        int gr = r0 + quad * 4 + rg;
        dv[rg] = dinv[gr < nrows ? gr : 0];
    }
#pragma unroll
    for (int ct = 0; ct < CT; ct++) {
#pragma unroll
        for (int rg = 0; rg < 4; rg++)
            tile[wave][quad * 4 + rg][ct * 16 + m] = f2bf(acc[ct][rg] * dv[rg]);
    }
    int srow = lane >> 2;
    int grow = r0 + srow;
    if (grow < nrows) {
        constexpr int CH2 = COLS / 32;
#pragma unroll
        for (int j8 = 0; j8 < CH2; j8++) {
            int c = (lane & 3) * 8 + j8 * 32;
            uint4 v = *(const uint4*)&tile[wave][srow][c];
            *(uint4*)(G + (size_t)grow * COLS + c) = v;
        }
    }
}

// ---------- aggregate: out[r] = pscale?*relu?(dinv[r]*(g[r] + sum_adj g[c])) ----------
// R8: wide dwordx4 loads. R15: packed f32x2 accumulators (neutral, kept).
// R16: PSCALE flag — layer-0 agg emits s0 = dinv*relu(dinv*sum) for the fused layers.
__device__ __forceinline__ f32x2 bfpair(unsigned int u) {
    union { unsigned int u; float f; } lo, hi;
    lo.u = u << 16;
    hi.u = u & 0xffff0000u;
    return (f32x2){lo.f, hi.f};
}
__device__ __forceinline__ void acc8p(f32x2* a, uint4 u) {
    a[0] += bfpair(u.x);
    a[1] += bfpair(u.y);
    a[2] += bfpair(u.z);
    a[3] += bfpair(u.w);
}

template <int D, bool RELU, bool PSCALE, bool FINAL>
__global__ __launch_bounds__(256) void k_agg(const unsigned short* __restrict__ g,
                                             const int* __restrict__ colS,
                                             const int* __restrict__ offs,
                                             const int* __restrict__ cnt,
                                             const float* __restrict__ dinv,
                                             unsigned short* __restrict__ obf,
                                             void* __restrict__ oraw,
                                             const int* __restrict__ dflag, int n) {
    constexpr int GRP = (D == 128) ? 4 : 8;   // neighbor rows per load instruction
    constexpr int LPR = 64 / GRP;             // lanes per row (16 or 8)
    int lane = threadIdx.x & 63;
    int node = blockIdx.x * 4 + (threadIdx.x >> 6);
    if (node >= n) return;
    int gq = lane / LPR;      // neighbor slot within a GRP-group
    int li = lane % LPR;      // 16B chunk within the row
    int start = offs[node];
    int deg = cnt[node];

    f32x2 a[4];
#pragma unroll
    for (int i = 0; i < 4; i++) a[i] = (f32x2){0.f, 0.f};

    if (gq == 0) {
        uint4 u = *(const uint4*)(g + (size_t)node * D + li * 8);
        acc8p(a, u);
    }

    for (int base = 0; base < deg; base += 64) {
        int rem = deg - base;
        int nb = rem < 64 ? rem : 64;
        int cidx = 0;
        if (lane < nb) cidx = colS[start + base + lane];
        int j = 0;
        if constexpr (D == 128) {
            for (; j + 8 <= nb; j += 8) {
                int ca = __shfl(cidx, j + gq);
                int cb = __shfl(cidx, j + 4 + gq);
                uint4 ua = *(const uint4*)(g + (size_t)ca * D + li * 8);
                uint4 ub = *(const uint4*)(g + (size_t)cb * D + li * 8);
                acc8p(a, ua);
                acc8p(a, ub);
            }
            for (; j < nb; j += 4) {
                int jj = j + gq;
                int cc = __shfl(cidx, jj < nb ? jj : (nb - 1));
                if (jj < nb) {
                    uint4 u = *(const uint4*)(g + (size_t)cc * D + li * 8);
                    acc8p(a, u);
                }
            }
        } else {
            for (; j + 8 <= nb; j += 8) {
                int cc = __shfl(cidx, j + gq);
                uint4 u = *(const uint4*)(g + (size_t)cc * D + li * 8);
                acc8p(a, u);
            }
            for (; j < nb; j += 8) {
                int jj = j + gq;
                int cc = __shfl(cidx, jj < nb ? jj : (nb - 1));
                if (jj < nb) {
                    uint4 u = *(const uint4*)(g + (size_t)cc * D + li * 8);
                    acc8p(a, u);
                }
            }
        }
    }

#pragma unroll
    for (int i = 0; i < 4; i++) {
        if constexpr (D == 64) {
            a[i].x += __shfl_xor(a[i].x, 8);
            a[i].y += __shfl_xor(a[i].y, 8);
        }
        a[i].x += __shfl_xor(a[i].x, 16);
        a[i].y += __shfl_xor(a[i].y, 16);
        a[i].x += __shfl_xor(a[i].x, 32);
        a[i].y += __shfl_xor(a[i].y, 32);
    }

    float s = dinv[node];
    f32x2 sv = {s, s};
#pragma unroll
    for (int i = 0; i < 4; i++) {
        a[i] *= sv;
        if constexpr (RELU)
            a[i] = (f32x2){fmaxf(a[i].x, 0.f), fmaxf(a[i].y, 0.f)};
        if constexpr (PSCALE) a[i] *= sv;
    }

    if (gq == 0) {
        uint4 o;
        o.x = (unsigned int)f2bf(a[0].x) | ((unsigned int)f2bf(a[0].y) << 16);
        o.y = (unsigned int)f2bf(a[1].x) | ((unsigned int)f2bf(a[1].y) << 16);
        o.z = (unsigned int)f2bf(a[2].x) | ((unsigned int)f2bf(a[2].y) << 16);
        o.w = (unsigned int)f2bf(a[3].x) | ((unsigned int)f2bf(a[3].y) << 16);
        *(uint4*)(obf + (size_t)node * D + li * 8) = o;
        if constexpr (FINAL) {
            if (*dflag) {
                *(uint4*)((unsigned short*)oraw + (size_t)node * D + li * 8) = o;
            } else {
                float* op = (float*)oraw + (size_t)node * D + li * 8;
                *(float4*)op = (float4){a[0].x, a[0].y, a[1].x, a[1].y};
                *(float4*)(op + 4) = (float4){a[2].x, a[2].y, a[3].x, a[3].y};
            }
        }
    }
}

// ---------- R16: fused conv layer (agg-first, by linearity agg(h@W) = agg(h)@W) ----------
// Input s[c] = dinv[c]*relu-form rows (128-dim bf16). Block = 16 destination nodes.
// Phase 1: 4 waves x 4 nodes gather-sum (same structure as k_agg D=128) -> LDS tile.
// Phase 2: MFMA 16x128 @ W (wave w owns ct = 2w, 2w+1); y = dinv[r]*(t@W).
// PSCALE: out = dinv*relu(y) (s-form for next fused layer); else out = y (pre-relu).
__device__ __forceinline__ void acc8s(float* a, uint4 u) {
    a[0] += bf2f(u.x); a[1] += bf2f(u.x >> 16);
    a[2] += bf2f(u.y); a[3] += bf2f(u.y >> 16);
    a[4] += bf2f(u.z); a[5] += bf2f(u.z >> 16);
    a[6] += bf2f(u.w); a[7] += bf2f(u.w >> 16);
}

template <bool PSCALE>
__global__ __launch_bounds__(256) void k_fused(const unsigned short* __restrict__ s,
                                               const unsigned short* __restrict__ Wp,
                                               const int* __restrict__ colS,
                                               const int* __restrict__ offs,
                                               const int* __restrict__ cnt,
                                               const float* __restrict__ dinv,
                                               unsigned short* __restrict__ out) {
    constexpr int CT = 8;  // COLS=128
    __shared__ unsigned short tile[16][136];
    __shared__ unsigned short otile[16][136];
    int t = threadIdx.x;
    int wave = t >> 6, lane = t & 63;
    int quad = lane >> 4, m = lane & 15;
    int gq = lane >> 4;   // GRP=4, LPR=16
    int li = lane & 15;
    int n0 = blockIdx.x * 16;

    // phase 1: gather-sum 4 nodes per wave
    for (int k = 0; k < 4; k++) {
        int node = n0 + wave * 4 + k;
        int start = offs[node];
        int deg = cnt[node];
        float a[8];
#pragma unroll
        for (int i = 0; i < 8; i++) a[i] = 0.f;
        if (gq == 0) {
            uint4 u = *(const uint4*)(s + (size_t)node * 128 + li * 8);
            acc8s(a, u);
        }
        for (int base = 0; base < deg; base += 64) {
            int rem = deg - base;
            int nb = rem < 64 ? rem : 64;
            int cidx = 0;
            if (lane < nb) cidx = colS[start + base + lane];
            int j = 0;
            for (; j + 8 <= nb; j += 8) {
                int ca = __shfl(cidx, j + gq);
                int cb = __shfl(cidx, j + 4 + gq);
                uint4 ua = *(const uint4*)(s + (size_t)ca * 128 + li * 8);
                uint4 ub = *(const uint4*)(s + (size_t)cb * 128 + li * 8);
                acc8s(a, ua);
                acc8s(a, ub);
            }
            for (; j < nb; j += 4) {
                int jj = j + gq;
                int cc = __shfl(cidx, jj < nb ? jj : (nb - 1));
                if (jj < nb) {
                    uint4 u = *(const uint4*)(s + (size_t)cc * 128 + li * 8);
                    acc8s(a, u);
                }
            }
        }
#pragma unroll
        for (int i = 0; i < 8; i++) {
            a[i] += __shfl_xor(a[i], 16);
            a[i] += __shfl_xor(a[i], 32);
        }
        if (gq == 0) {
            uint4 o;
            o.x = (unsigned int)f2bf(a[0]) | ((unsigned int)f2bf(a[1]) << 16);
            o.y = (unsigned int)f2bf(a[2]) | ((unsigned int)f2bf(a[3]) << 16);
            o.z = (unsigned int)f2bf(a[4]) | ((unsigned int)f2bf(a[5]) << 16);
            o.w = (unsigned int)f2bf(a[6]) | ((unsigned int)f2bf(a[7]) << 16);
            *(uint4*)&tile[wave * 4 + k][li * 8] = o;
        }
    }
    __syncthreads();

    // phase 2: A-frags from tile, MFMA with W (wave w -> ct = 2w, 2w+1)
    bf16x8 afr[4];
#pragma unroll
    for (int kt = 0; kt < 4; kt++)
        afr[kt] = *(const bf16x8*)&tile[m][kt * 32 + quad * 8];

    f32x4 acc0 = (f32x4){0.f, 0.f, 0.f, 0.f};
    f32x4 acc1 = (f32x4){0.f, 0.f, 0.f, 0.f};
    int ct0 = 2 * wave, ct1 = 2 * wave + 1;
#pragma unroll
    for (int kt = 0; kt < 4; kt++) {
        bf16x8 b0 = *(const bf16x8*)(Wp + (((size_t)kt * CT + ct0) * 64 + lane) * 8);
        bf16x8 b1 = *(const bf16x8*)(Wp + (((size_t)kt * CT + ct1) * 64 + lane) * 8);
        acc0 = __builtin_amdgcn_mfma_f32_16x16x32_bf16(afr[kt], b0, acc0, 0, 0, 0);
        acc1 = __builtin_amdgcn_mfma_f32_16x16x32_bf16(afr[kt], b1, acc1, 0, 0, 0);
    }

    float dv[4];
#pragma unroll
    for (int rg = 0; rg < 4; rg++) dv[rg] = dinv[n0 + quad * 4 + rg];
#pragma unroll
    for (int rg = 0; rg < 4; rg++) {
        float y0 = acc0[rg] * dv[rg];
        float y1 = acc1[rg] * dv[rg];
        if constexpr (PSCALE) {
            y0 = dv[rg] * fmaxf(y0, 0.f);
            y1 = dv[rg] * fmaxf(y1, 0.f);
        }
        otile[quad * 4 + rg][ct0 * 16 + m] = f2bf(y0);
        otile[quad * 4 + rg][ct1 * 16 + m] = f2bf(y1);
    }
    __syncthreads();

    int row = t >> 4, ci = (t & 15) * 8;
    uint4 v = *(const uint4*)&otile[row][ci];
    *(uint4*)(out + (size_t)(n0 + row) * 128 + ci) = v;
}

// ---------- column sums (vectorized bf16x8 loads + LDS reduce) ----------
template <int D>
__global__ __launch_bounds__(256) void k_colsum(const unsigned short* __restrict__ in,
                                                float* __restrict__ colsum, int n) {
    constexpr int CG = D / 8;
    constexpr int RPB = 256 / CG;
    __shared__ float red[RPB][D];
    int t = threadIdx.x;
    int cg = t % CG, r0 = t / CG;
    int c0 = cg * 8;
    float a[8];
#pragma unroll
    for (int i = 0; i < 8; i++) a[i] = 0.f;
    for (int r = blockIdx.x * RPB + r0; r < n; r += gridDim.x * RPB) {
        bf16x8 u = *(const bf16x8*)(in + (size_t)r * D + c0);
#pragma unroll
        for (int i = 0; i < 8; i++) a[i] += bf2f((unsigned short)u[i]);
    }
#pragma unroll
    for (int i = 0; i < 8; i++) red[r0][c0 + i] = a[i];
    __syncthreads();
    if (t < D) {
        float s = 0.f;
#pragma unroll
        for (int r = 0; r < RPB; r++) s += red[r][t];
        atomicAdd(&colsum[t], s);
    }
}

// ---------- MFMA covariance (see R6 notes: no dynamic register indexing) ----------
template <int D>
__global__ __launch_bounds__(256) void k_cov2(const unsigned short* __restrict__ in,
                                              const float* __restrict__ colsum,
                                              float* __restrict__ part, int n, int nblocks) {
    constexpr int CT = D / 16;
    constexpr int TPW = (D == 128) ? 2 : 1;
    constexpr int CG = D / 8;
    __shared__ unsigned int lds32[D * 16];
    __shared__ float smean[D];

    int t = threadIdx.x;
    int wave = t >> 6, lane = t & 63;
    int quad = lane >> 4, m = lane & 15;

    if (t < D) smean[t] = colsum[t] * (1.0f / (float)NN);
    __syncthreads();

    f32x4 accA[CT], accB[CT];
#pragma unroll
    for (int tc = 0; tc < CT; tc++) {
        accA[tc] = (f32x4){0.f, 0.f, 0.f, 0.f};
        accB[tc] = (f32x4){0.f, 0.f, 0.f, 0.f};
    }

    bool stager = (t < 16 * CG);
    int kp = stager ? (t / CG) : 0;
    int c0 = stager ? ((t % CG) * 8) : 0;
    int slot = (((kp >> 2) + (c0 >> 3)) & 3) * 4 + (kp & 3);
    float sm[8];
#pragma unroll
    for (int i = 0; i < 8; i++) sm[i] = smean[c0 + i];

    int ca0 = (wave * TPW) * 16 + m;
    int ga0 = (quad + (ca0 >> 3)) & 3;
    int ca1 = ca0 + 16;
    int ga1 = (quad + (ca1 >> 3)) & 3;

    int nchunks = (n + 31) / 32;
    for (int ch = blockIdx.x; ch < nchunks; ch += nblocks) {
        int k0 = ch * 32;
        if (stager) {
            int k = k0 + 2 * kp;
            bf16x8 u0 = (bf16x8)0, u1 = (bf16x8)0;
            bool ok0 = (k < n), ok1 = (k + 1 < n);
            if (ok0) u0 = *(const bf16x8*)(in + (size_t)k * D + c0);
            if (ok1) u1 = *(const bf16x8*)(in + (size_t)(k + 1) * D + c0);
#pragma unroll
            for (int i = 0; i < 8; i++) {
                float a = ok0 ? (bf2f((unsigned short)u0[i]) - sm[i]) : 0.f;
                float b = ok1 ? (bf2f((unsigned short)u1[i]) - sm[i]) : 0.f;
                lds32[(c0 + i) * 16 + slot] = (unsigned int)f2bf(a) | ((unsigned int)f2bf(b) << 16);
            }
        }
        __syncthreads();

        bf16x8 bfr[CT];
#pragma unroll
        for (int tc = 0; tc < CT; tc++) {
            int c = tc * 16 + m;
            int grp = (quad + (c >> 3)) & 3;
            bfr[tc] = *(const bf16x8*)&lds32[c * 16 + grp * 4];
        }
        bf16x8 afr0 = *(const bf16x8*)&lds32[ca0 * 16 + ga0 * 4];
#pragma unroll
        for (int tc = 0; tc < CT; tc++)
            accA[tc] = __builtin_amdgcn_mfma_f32_16x16x32_bf16(afr0, bfr[tc], accA[tc], 0, 0, 0);
        if constexpr (TPW == 2) {
            bf16x8 afr1 = *(const bf16x8*)&lds32[ca1 * 16 + ga1 * 4];
#pragma unroll
            for (int tc = 0; tc < CT; tc++)
                accB[tc] = __builtin_amdgcn_mfma_f32_16x16x32_bf16(afr1, bfr[tc], accB[tc], 0, 0, 0);
        }
        __syncthreads();
    }

    float* p = part + (size_t)blockIdx.x * D * D;
    int tr0 = wave * TPW;
#pragma unroll
    for (int tc = 0; tc < CT; tc++) {
#pragma unroll
        for (int rg = 0; rg < 4; rg++) {
            int cj = tc * 16 + m;
            p[(tr0 * 16 + quad * 4 + rg) * D + cj] = accA[tc][rg];
            if constexpr (TPW == 2)
                p[((tr0 + 1) * 16 + quad * 4 + rg) * D + cj] = accB[tc][rg];
        }
    }
}

// ---------- partial-covariance reduction (R7: 2-D decomposition) ----------
template <int D>
__global__ __launch_bounds__(256) void k_covred(const float* __restrict__ part,
                                                float* __restrict__ cov, int nblocks) {
    __shared__ float red[256];
    int t = threadIdx.x;
    int il = t & 63;
    int bs = t >> 6;
    int idx = blockIdx.x * 64 + il;
    float s = 0.f;
    for (int b = bs; b < nblocks; b += 4)
        s += part[(size_t)b * D * D + idx];
    red[t] = s;
    __syncthreads();
    if (t < 64)
        cov[idx] = red[t] + red[t + 64] + red[t + 128] + red[t + 192];
}

template <int D>
__global__ __launch_bounds__(256) void k_fin(const float* __restrict__ cov,
                                             void* __restrict__ out, long long idx,
                                             const int* __restrict__ dflag) {
    __shared__ float sd[D];
    __shared__ float red[256];
    int t = threadIdx.x;
    if (t < D) sd[t] = sqrtf(fmaxf(cov[t * D + t], 1e-12f));
    __syncthreads();
    float s = 0.f;
    for (int i2 = t; i2 < D * D; i2 += 256) {
        int i = i2 / D, j = i2 % D;
        if (j > i) s += fabsf(cov[i2] / (sd[i] * sd[j]));
    }
    red[t] = s;
    __syncthreads();
    for (int off = 128; off > 0; off >>= 1) {
        if (t < off) red[t] += red[t + off];
        __syncthreads();
    }
    if (t == 0) {
        float v = red[0] / (float)(D * (D - 1) / 2);
        if (*dflag) ((unsigned short*)out)[idx] = f2bf(v);
        else        ((float*)out)[idx] = v;
    }
}

// ---------- launch ----------
extern "C" void kernel_launch(void* const* d_in, const int* in_sizes, int n_in,
                              void* d_out, int out_size, void* d_ws, size_t ws_size,
                              hipStream_t stream) {
    const void* x = d_in[0];
    const int* ei = (const int*)d_in[1];

    int E = in_sizes[1] / 2;
    const int* row = ei;
    const int* col = ei + E;

    char* w = (char*)d_ws;
    auto carve = [&](size_t bytes) {
        void* p = (void*)w;
        w += (bytes + 255) & ~(size_t)255;
        return p;
    };
    int* cnt = (int*)carve((size_t)NN * 4);
    int* offs = (int*)carve((size_t)NN * 4);
    int* bsum = (int*)carve(512 * 4);
    int* colS = (int*)carve((size_t)E * 4);
    float* dinv = (float*)carve((size_t)NN * 4);
    float* colsum = (float*)carve(HD * 4);
    float* covs = (float*)carve(HD * HD * 4);
    int* dflag = (int*)carve(256);
    unsigned short* wc = (unsigned short*)carve((size_t)(FIN * HD + HD * HD * 2 + HD * CD) * 2);
    unsigned short* bufA = (unsigned short*)carve((size_t)NN * HD * 2);
    unsigned short* bufB = (unsigned short*)carve((size_t)NN * HD * 2);

    unsigned short* wc0 = wc;              // 256x128 packed
    unsigned short* wc1 = wc + FIN * HD;   // 128x128 packed
    unsigned short* wc2 = wc1 + HD * HD;   // 128x128 packed
    unsigned short* wc3 = wc2 + HD * HD;   // 128x64 packed

    float* part = (float*)bufB;   // cov partials alias bufB (dead during corr)
    int* chp = (int*)bufB;        // chunk-prefix partials alias bufB (dead in preprocessing)
    const int NBC = 250;

    int nchunks = (NN + 255) / 256;
    int GB = (NN + 63) / 64;

    // dtype detection + weight packing
    k_detect<<<1, 256, 0, stream>>>((const unsigned short*)x, dflag);
    k_packW<256, 128><<<(FIN * HD) / 256, 256, 0, stream>>>(d_in[2], wc0, dflag);
    k_packW<128, 128><<<(HD * HD) / 256, 256, 0, stream>>>(d_in[3], wc1, dflag);
    k_packW<128, 128><<<(HD * HD) / 256, 256, 0, stream>>>(d_in[4], wc2, dflag);
    k_packW<128, 64><<<(HD * CD) / 256, 256, 0, stream>>>(d_in[5], wc3, dflag);

    // preprocessing (CSR by destination) — zero global atomics (R9), XCD-aligned (R10),
    // 1024-thread latency hiding (R11)
    k_histL<<<RG * CH, 1024, 0, stream>>>(row, chp, E);
    k_histpre<<<nchunks, 256, 0, stream>>>(chp, cnt, NN);
    k_scan_a<<<nchunks, 256, 0, stream>>>(cnt, bsum, NN);
    k_scan_b<<<1, 512, 0, stream>>>(bsum, nchunks);
    k_scan_c<<<nchunks, 256, 0, stream>>>(cnt, bsum, offs, NN);
    k_scatL<<<RG * CH, 1024, 0, stream>>>(row, col, offs, chp, colS, E);
    k_dinv<<<nchunks, 256, 0, stream>>>(cnt, dinv, NN);

    // layer 0: gemm-first (256->128), agg emits s0 = dinv*relu(dinv*sum)
    k_gemm<256, 128, false, 2><<<GB, 256, 0, stream>>>(x, wc0, dinv, bufB, NN, dflag);
    k_agg<128, true, true, false><<<NN / 4, 256, 0, stream>>>(bufB, colS, offs, cnt, dinv, bufA, nullptr, dflag, NN);

    // layers 1,2: fused agg-first conv (R16) — gemm1/agg1/gemm2/agg2 replaced
    k_fused<true><<<NN / 16, 256, 0, stream>>>(bufA, wc1, colS, offs, cnt, dinv, bufB);   // s1
    k_fused<false><<<NN / 16, 256, 0, stream>>>(bufB, wc2, colS, offs, cnt, dinv, bufA);  // y2 (pre-relu)

    // corr_2 on bufA (bf16, D=128)
    hipMemsetAsync(colsum, 0, HD * 4, stream);
    k_colsum<128><<<64, 256, 0, stream>>>(bufA, colsum, NN);
    k_cov2<128><<<NBC, 256, 0, stream>>>(bufA, colsum, part, NN, NBC);
    k_covred<128><<<(HD * HD) / 64, 256, 0, stream>>>(part, covs, NBC);
    k_fin<128><<<1, 256, 0, stream>>>(covs, d_out, (long long)NN * CD, dflag);

    // layer 3: relu(bufA) @ W3 -> bufB ; aggregate -> d_out (+ bf16 mirror in bufA)
    k_gemm<128, 64, true, 0><<<GB, 256, 0, stream>>>(bufA, wc3, dinv, bufB, NN, dflag);
    k_agg<64, false, false, true><<<NN / 4, 256, 0, stream>>>(bufB, colS, offs, cnt, dinv, bufA, d_out, dflag, NN);

    // corr on final output (bf16 mirror in bufA, D=64)
    hipMemsetAsync(colsum, 0, HD * 4, stream);
    k_colsum<64><<<64, 256, 0, stream>>>(bufA, colsum, NN);
    k_cov2<64><<<NBC, 256, 0, stream>>>(bufA, colsum, part, NN, NBC);
    k_covred<64><<<(CD * CD) / 64, 256, 0, stream>>>(part, covs, NBC);
    k_fin<64><<<1, 256, 0, stream>>>(covs, d_out, (long long)NN * CD + 1, dflag);
}